// Round 13
// baseline (886.452 us; speedup 1.0000x reference)
//
#include <hip/hip_runtime.h>
#include <hip/hip_fp16.h>

#define BATCH 2
#define D_MODEL 1024
#define NH 16
#define DK 64
#define SEQ 2048

typedef _Float16 f16;
typedef __attribute__((ext_vector_type(8))) _Float16 f16x8;
typedef __attribute__((ext_vector_type(4))) _Float16 f16x4;
typedef __attribute__((ext_vector_type(4))) float f32x4;

// ---------------------------------------------------------------------------
// Fused QKV GEMM: C = X(f32)[4096][1024] @ [Wq;Wk;Wv]^T  -> N = 3072
// Q,K segments: [b][h][s][dk] with fused RoPE.
// V segment: TRANSPOSED layout [b][h][d][s]; tile is transposed through LDS
// (reusing the staging buffer) so the global V^T store is coalesced b128.
// 128x128 tile, BK=32, 4 waves (2x2). grid (24, 32) = 768 blocks = 3/CU.
// ---------------------------------------------------------------------------
__global__ __launch_bounds__(256) void gemm_qkv(const float* __restrict__ X,
                                                const float* __restrict__ Wq,
                                                const float* __restrict__ Wk,
                                                const float* __restrict__ Wv,
                                                f16* __restrict__ WS)
{
    constexpr int BK  = 32;
    constexpr int LDP = BK + 8;  // 80B rows (16B-aligned)
    __shared__ f16 SM[2 * 128 * LDP];   // 20480 B, aliased: As | Bs, later Ts
    f16* As = SM;
    f16* Bs = SM + 128 * LDP;

    const int tid  = threadIdx.x;
    const int lane = tid & 63;
    const int wave = tid >> 6;
    const int wm   = wave >> 1, wn = wave & 1;
    const int g    = lane >> 4;
    const int l15  = lane & 15;
    const int m0   = blockIdx.y * 128;
    const int n0   = blockIdx.x * 128;     // global col in 0..3071
    const int seg  = n0 >> 10;             // 0=Q 1=K 2=V (whole block in one seg)
    const int nloc = n0 & 1023;
    const float* __restrict__ W = (seg == 0) ? Wq : (seg == 1 ? Wk : Wv);
    f16* __restrict__ Out = WS + (size_t)seg * BATCH * SEQ * D_MODEL;

    f32x4 acc[4][4] = {};

    const int srow = tid >> 3;        // 0..31
    const int scol = (tid & 7) * 4;   // 0,4,...,28

    for (int k0 = 0; k0 < 1024; k0 += BK) {
        __syncthreads();
        #pragma unroll
        for (int p = 0; p < 4; ++p) {
            int r = p * 32 + srow;
            float4 v = *(const float4*)(X + (size_t)(m0 + r) * 1024 + k0 + scol);
            f16x4 h; h[0]=(f16)v.x; h[1]=(f16)v.y; h[2]=(f16)v.z; h[3]=(f16)v.w;
            *(f16x4*)(As + r * LDP + scol) = h;
            float4 w = *(const float4*)(W + (size_t)(nloc + r) * 1024 + k0 + scol);
            f16x4 hw; hw[0]=(f16)w.x; hw[1]=(f16)w.y; hw[2]=(f16)w.z; hw[3]=(f16)w.w;
            *(f16x4*)(Bs + r * LDP + scol) = hw;
        }
        __syncthreads();

        const int kc = g * 8;
        f16x8 a[4], b[4];
        #pragma unroll
        for (int i = 0; i < 4; ++i) {
            a[i] = *(const f16x8*)(As + (wm*64 + i*16 + l15) * LDP + kc);
            b[i] = *(const f16x8*)(Bs + (wn*64 + i*16 + l15) * LDP + kc);
        }
        #pragma unroll
        for (int i = 0; i < 4; ++i)
            #pragma unroll
            for (int j = 0; j < 4; ++j)
                acc[i][j] = __builtin_amdgcn_mfma_f32_16x16x32_f16(a[i], b[j], acc[i][j], 0, 0, 0);
    }

    const int rbase = m0 + wm * 64 + g * 4;
    const int cbase = nloc + wn * 64 + l15;
    if (seg < 2) {
        // Q,K: RoPE via adjacent-lane pairing (col parity == lane parity)
        #pragma unroll
        for (int j = 0; j < 4; ++j) {
            const int o  = cbase + j * 16;        // col within segment
            const int hh = o >> 6;
            const int d  = o & 63;
            const float freq = powf(10000.f, -(float)(d >> 1) * (1.f / 32.f));
            #pragma unroll
            for (int i = 0; i < 4; ++i) {
                #pragma unroll
                for (int r = 0; r < 4; ++r) {
                    const int row = rbase + i * 16 + r;
                    const int b   = row >> 11;
                    const int s   = row & 2047;
                    float v = acc[i][j][r];
                    float partner = __shfl_xor(v, 1);
                    float ang = (float)s * freq;
                    float sn, cs;
                    sincosf(ang, &sn, &cs);
                    float outv = (d & 1) ? (partner * sn + v * cs) : (v * cs - partner * sn);
                    Out[((size_t)(b * NH + hh) * SEQ + s) * DK + d] = (f16)outv;
                }
            }
        }
    } else {
        // V: transpose tile through LDS (two 64-col passes), coalesced V^T store.
        constexpr int LDT = 65;          // stride f16; 2-way-free read pattern
        const int s0 = m0 & 2047;
        const int bb = m0 >> 11;
        f16* Ts = SM;                    // 128 x 65 f16 = 16640 B <= 20480 B
        #pragma unroll
        for (int h = 0; h < 2; ++h) {
            __syncthreads();
            if (wn == h) {
                #pragma unroll
                for (int j = 0; j < 4; ++j)
                    #pragma unroll
                    for (int i = 0; i < 4; ++i)
                        #pragma unroll
                        for (int r = 0; r < 4; ++r) {
                            const int rl = wm * 64 + i * 16 + g * 4 + r;   // s-local
                            const int cl = j * 16 + l15;                   // d-local (0..63)
                            Ts[rl * LDT + cl] = (f16)acc[i][j][r];
                        }
            }
            __syncthreads();
            const int hh = (nloc >> 6) + h;
            #pragma unroll
            for (int it = 0; it < 4; ++it) {
                const int c  = tid + it * 256;
                const int dl = c >> 4;            // 0..63
                const int sc = (c & 15) * 8;      // 0..120
                f16x8 v;
                #pragma unroll
                for (int e = 0; e < 8; ++e) v[e] = Ts[(sc + e) * LDT + dl];
                *(f16x8*)(Out + ((size_t)((bb * NH + hh) * DK + dl)) * SEQ + s0 + sc) = v;
            }
        }
    }
}

// ---------------------------------------------------------------------------
// Flash attention, in-register online softmax.
// Per block: 64 q-rows, 4 waves (16 rows each), KV tiles of 64.
// K row-major [k][d]; V read from TRANSPOSED global [d][s] -> Vt[d][k],
// both staged with coalesced f16x8 loads + ds_write_b128 (no scalar stores).
// Softmax: C-layout row (q) lives in 16 contiguous lanes -> shfl_xor reduce.
// P goes through LDS (Pt) only for the C->A fragment relayout (same wave,
// no barrier needed).  2 barriers per kv-tile.
// Heavy-first block order: qb = nqb-1-blockIdx.x (LPT scheduling).
// ---------------------------------------------------------------------------
__global__ __launch_bounds__(256) void attn(const f16* __restrict__ Q,
                                            const f16* __restrict__ K,
                                            const f16* __restrict__ VT,
                                            f16* __restrict__ O)
{
    constexpr int SP = 72;              // f16 stride = 144B (16B aligned)
    __shared__ f16 Kt[64 * SP];
    __shared__ f16 Vt[64 * SP];         // [d][k]
    __shared__ f16 Pt[64 * SP];

    const int tid  = threadIdx.x;
    const int lane = tid & 63;
    const int w    = tid >> 6;
    const int g    = lane >> 4;         // 0..3
    const int l15  = lane & 15;
    const int qb = gridDim.x - 1 - blockIdx.x;   // heavy-first
    const int hh = blockIdx.y, b = blockIdx.z;
    const int q0 = qb * 64;
    const size_t base = (size_t)(b * NH + hh) * SEQ * DK;

    // Q fragments (A operand): row = q0 + w*16 + l15, k chunks of 8
    f16x8 qf[2];
    {
        const f16* qp = Q + base + (size_t)(q0 + w * 16 + l15) * DK + g * 8;
        qf[0] = *(const f16x8*)(qp);
        qf[1] = *(const f16x8*)(qp + 32);
    }
    f32x4 acc[4] = {};
    float m_reg[4] = {-INFINITY, -INFINITY, -INFINITY, -INFINITY};
    float l_reg[4] = {0.f, 0.f, 0.f, 0.f};

    const int srow = tid >> 3;          // 0..31 within 256 threads
    const int sco  = (tid & 7) * 8;     // 0..56

    for (int kb = 0; kb <= qb; ++kb) {
        __syncthreads();
        // stage K [k][d] and V^T [d][k], both coalesced b128
        {
            #pragma unroll
            for (int it = 0; it < 2; ++it) {
                const int rr = it * 32 + srow;  // 0..63
                f16x8 kv = *(const f16x8*)(K + base + (size_t)(kb * 64 + rr) * DK + sco);
                *(f16x8*)(Kt + rr * SP + sco) = kv;
                f16x8 vv = *(const f16x8*)(VT + base + (size_t)rr * SEQ + kb * 64 + sco);
                *(f16x8*)(Vt + rr * SP + sco) = vv;
            }
        }
        __syncthreads();

        // QK^T (C layout: col k = l15+16*nt, row q = w*16 + g*4 + r)
        f32x4 s[4];
        #pragma unroll
        for (int nt = 0; nt < 4; ++nt) {
            f32x4 z = {};
            const f16* kp = Kt + (nt * 16 + l15) * SP + g * 8;
            z = __builtin_amdgcn_mfma_f32_16x16x32_f16(qf[0], *(const f16x8*)kp,        z, 0, 0, 0);
            z = __builtin_amdgcn_mfma_f32_16x16x32_f16(qf[1], *(const f16x8*)(kp + 32), z, 0, 0, 0);
            s[nt] = z;
        }

        // in-register online softmax (per r: row q = w*16+g*4+r)
        #pragma unroll
        for (int r = 0; r < 4; ++r) {
            const int qloc = w * 16 + g * 4 + r;
            float va[4];
            #pragma unroll
            for (int nt = 0; nt < 4; ++nt) {
                float sv = s[nt][r] * 0.125f;
                if (kb == qb && (nt * 16 + l15) > qloc) sv = -INFINITY;
                va[nt] = sv;
            }
            float mx = fmaxf(fmaxf(va[0], va[1]), fmaxf(va[2], va[3]));
            mx = fmaxf(mx, __shfl_xor(mx, 1));
            mx = fmaxf(mx, __shfl_xor(mx, 2));
            mx = fmaxf(mx, __shfl_xor(mx, 4));
            mx = fmaxf(mx, __shfl_xor(mx, 8));
            const float mnew = fmaxf(m_reg[r], mx);
            const float scl  = __expf(m_reg[r] - mnew);
            m_reg[r] = mnew;
            float ps = 0.f;
            #pragma unroll
            for (int nt = 0; nt < 4; ++nt) {
                float p = __expf(va[nt] - mnew);
                ps += p;
                Pt[qloc * SP + nt * 16 + l15] = (f16)p;
            }
            ps += __shfl_xor(ps, 1);
            ps += __shfl_xor(ps, 2);
            ps += __shfl_xor(ps, 4);
            ps += __shfl_xor(ps, 8);
            l_reg[r] = l_reg[r] * scl + ps;
            #pragma unroll
            for (int nt = 0; nt < 4; ++nt) acc[nt][r] *= scl;
        }

        // PV: P A-fragment from Pt (same-wave rows, no barrier),
        //     V^T B-fragment straight from Vt (no swizzle).
        {
            f16x8 pa[2];
            const f16* pp = Pt + (w * 16 + l15) * SP + g * 8;
            pa[0] = *(const f16x8*)pp;
            pa[1] = *(const f16x8*)(pp + 32);
            #pragma unroll
            for (int nt = 0; nt < 4; ++nt) {
                const f16* vp = Vt + (nt * 16 + l15) * SP + g * 8;
                acc[nt] = __builtin_amdgcn_mfma_f32_16x16x32_f16(pa[0], *(const f16x8*)vp,        acc[nt], 0, 0, 0);
                acc[nt] = __builtin_amdgcn_mfma_f32_16x16x32_f16(pa[1], *(const f16x8*)(vp + 32), acc[nt], 0, 0, 0);
            }
        }
    }

    // epilogue: O[b][s][hh*64+d] = acc / l   (l replicated across 16 lanes)
    #pragma unroll
    for (int r = 0; r < 4; ++r) {
        const float inv = 1.f / l_reg[r];
        const int s = q0 + w * 16 + g * 4 + r;
        #pragma unroll
        for (int nt = 0; nt < 4; ++nt) {
            const int d = nt * 16 + l15;
            O[((size_t)(b * SEQ + s)) * D_MODEL + hh * 64 + d] = (f16)(acc[nt][r] * inv);
        }
    }
}

// ---------------------------------------------------------------------------
// GEMM2: out(f32) = AO(f16)[4096][1024] @ Wo(f32)[1024][1024]^T
// BM=64, BN=128 -> grid (8,64) = 512 blocks = 2/CU.  4 waves 2x2, wave 32x64.
// ---------------------------------------------------------------------------
__global__ __launch_bounds__(256) void gemm_out(const f16* __restrict__ A,
                                                const float* __restrict__ W,
                                                float* __restrict__ Cout)
{
    constexpr int BK  = 32;
    constexpr int LDP = BK + 8;
    __shared__ f16 As[64 * LDP];
    __shared__ f16 Bs[128 * LDP];

    const int tid  = threadIdx.x;
    const int lane = tid & 63;
    const int wave = tid >> 6;
    const int wm   = wave >> 1, wn = wave & 1;     // wave tile 32x64
    const int m0   = blockIdx.y * 64;
    const int n0   = blockIdx.x * 128;

    f32x4 acc[2][4] = {};

    const int srow = tid >> 3;        // 0..31 (B stage)
    const int scol = (tid & 7) * 4;
    const int arow = tid >> 2;        // 0..63 (A stage)
    const int acol = (tid & 3) * 8;

    for (int k0 = 0; k0 < 1024; k0 += BK) {
        __syncthreads();
        {
            f16x8 v = *(const f16x8*)(A + (size_t)(m0 + arow) * 1024 + k0 + acol);
            *(f16x8*)(As + arow * LDP + acol) = v;
        }
        #pragma unroll
        for (int p = 0; p < 4; ++p) {
            int r = p * 32 + srow;
            float4 w = *(const float4*)(W + (size_t)(n0 + r) * 1024 + k0 + scol);
            f16x4 hw; hw[0]=(f16)w.x; hw[1]=(f16)w.y; hw[2]=(f16)w.z; hw[3]=(f16)w.w;
            *(f16x4*)(Bs + r * LDP + scol) = hw;
        }
        __syncthreads();

        const int kc = (lane >> 4) * 8;
        f16x8 a[2], b[4];
        #pragma unroll
        for (int i = 0; i < 2; ++i)
            a[i] = *(const f16x8*)(As + (wm*32 + i*16 + (lane & 15)) * LDP + kc);
        #pragma unroll
        for (int j = 0; j < 4; ++j)
            b[j] = *(const f16x8*)(Bs + (wn*64 + j*16 + (lane & 15)) * LDP + kc);
        #pragma unroll
        for (int i = 0; i < 2; ++i)
            #pragma unroll
            for (int j = 0; j < 4; ++j)
                acc[i][j] = __builtin_amdgcn_mfma_f32_16x16x32_f16(a[i], b[j], acc[i][j], 0, 0, 0);
    }

    #pragma unroll
    for (int i = 0; i < 2; ++i)
        #pragma unroll
        for (int j = 0; j < 4; ++j)
            #pragma unroll
            for (int r = 0; r < 4; ++r) {
                const int row = m0 + wm*32 + i*16 + ((lane >> 4) * 4) + r;
                const int col = n0 + wn*64 + j*16 + (lane & 15);
                Cout[(size_t)row * 1024 + col] = acc[i][j][r];
            }
}

// ---------------------------------------------------------------------------
extern "C" void kernel_launch(void* const* d_in, const int* in_sizes, int n_in,
                              void* d_out, int out_size, void* d_ws, size_t ws_size,
                              hipStream_t stream)
{
    const float* x  = (const float*)d_in[0];
    const float* Wq = (const float*)d_in[1];
    const float* Wk = (const float*)d_in[2];
    const float* Wv = (const float*)d_in[3];
    const float* Wo = (const float*)d_in[4];
    float* out = (float*)d_out;

    const size_t NE = (size_t)BATCH * SEQ * D_MODEL;  // 4194304
    f16* Qr = (f16*)d_ws;
    f16* Kr = Qr + NE;
    f16* VTr = Kr + NE;   // transposed V: [b][h][d][s]
    f16* AO = VTr + NE;

    dim3 blk(256);
    gemm_qkv<<<dim3(24, 32), blk, 0, stream>>>(x, Wq, Wk, Wv, Qr);

    attn<<<dim3(SEQ / 64, NH, BATCH), blk, 0, stream>>>(Qr, Kr, VTr, AO);

    gemm_out<<<dim3(8, 64), blk, 0, stream>>>(AO, Wo, out);
}

// Round 15
// 754.828 us; speedup vs baseline: 1.1744x; 1.1744x over previous
//
#include <hip/hip_runtime.h>
#include <hip/hip_fp16.h>

#define BATCH 2
#define D_MODEL 1024
#define NH 16
#define DK 64
#define SEQ 2048

typedef _Float16 f16;
typedef __attribute__((ext_vector_type(8))) _Float16 f16x8;
typedef __attribute__((ext_vector_type(4))) _Float16 f16x4;
typedef __attribute__((ext_vector_type(4))) float f32x4;

// ---------------------------------------------------------------------------
// tof16: convert Wq,Wk,Wv,Wo (each 1024x1024 f32) to f16 into Wh (contiguous).
// 2048 blocks x 256 threads x 8 elems.
// ---------------------------------------------------------------------------
__global__ __launch_bounds__(256) void tof16(const float* __restrict__ a,
                                             const float* __restrict__ b,
                                             const float* __restrict__ c,
                                             const float* __restrict__ d,
                                             f16* __restrict__ dst)
{
    const int u = blockIdx.x;           // 0..2047
    const int m = u >> 9;               // matrix id
    const float* __restrict__ src = (m == 0) ? a : (m == 1) ? b : (m == 2) ? c : d;
    const int off = (u & 511) * 2048 + threadIdx.x * 8;
    float4 v0 = *(const float4*)(src + off);
    float4 v1 = *(const float4*)(src + off + 4);
    f16x8 h;
    h[0]=(f16)v0.x; h[1]=(f16)v0.y; h[2]=(f16)v0.z; h[3]=(f16)v0.w;
    h[4]=(f16)v1.x; h[5]=(f16)v1.y; h[6]=(f16)v1.z; h[7]=(f16)v1.w;
    *(f16x8*)(dst + (size_t)m * 1048576 + off) = h;
}

// ---------------------------------------------------------------------------
// Fused QKV GEMM: C = X(f32)[4096][1024] @ Wh(f16,[Wq;Wk;Wv])^T -> N = 3072
// Q,K segments: [b][h][s][dk] with fused RoPE.
// V segment: TRANSPOSED [b][h][d][s] via LDS transpose, coalesced b128 store.
// 128x128 tile, BK=32, 4 waves (2x2). 1D grid 768, XCD-bijective swizzle:
// each XCD gets 96 contiguous wgids = 4 m-panels -> X panel cached in its L2.
// ---------------------------------------------------------------------------
__global__ __launch_bounds__(256) void gemm_qkv(const float* __restrict__ X,
                                                const f16* __restrict__ Wh,
                                                f16* __restrict__ WS)
{
    constexpr int BK  = 32;
    constexpr int LDP = BK + 8;  // 80B rows (16B-aligned)
    __shared__ f16 SM[2 * 128 * LDP];   // aliased: As | Bs, later Ts
    f16* As = SM;
    f16* Bs = SM + 128 * LDP;

    const int tid  = threadIdx.x;
    const int lane = tid & 63;
    const int wave = tid >> 6;
    const int wm   = wave >> 1, wn = wave & 1;
    const int g    = lane >> 4;
    const int l15  = lane & 15;

    // XCD-bijective swizzle (768 % 8 == 0, 96 wgids per XCD, bx fastest)
    const int wg   = blockIdx.x;
    const int wgid = (wg & 7) * 96 + (wg >> 3);
    const int bx   = wgid % 24;
    const int by   = wgid / 24;
    const int m0   = by * 128;
    const int n0   = bx * 128;             // global col in 0..3071
    const int seg  = n0 >> 10;             // 0=Q 1=K 2=V
    const int nloc = n0 & 1023;
    const f16* __restrict__ W = Wh + (size_t)seg * 1048576;
    f16* __restrict__ Out = WS + (size_t)seg * BATCH * SEQ * D_MODEL;

    f32x4 acc[4][4] = {};

    const int srow = tid >> 3;        // 0..31  (A stage, f32)
    const int scol = (tid & 7) * 4;   // 0..28
    const int brow = tid >> 2;        // 0..63  (B stage, f16)
    const int bcol = (tid & 3) * 8;   // 0..24

    for (int k0 = 0; k0 < 1024; k0 += BK) {
        __syncthreads();
        #pragma unroll
        for (int p = 0; p < 4; ++p) {
            int r = p * 32 + srow;
            float4 v = *(const float4*)(X + (size_t)(m0 + r) * 1024 + k0 + scol);
            f16x4 h; h[0]=(f16)v.x; h[1]=(f16)v.y; h[2]=(f16)v.z; h[3]=(f16)v.w;
            *(f16x4*)(As + r * LDP + scol) = h;
        }
        #pragma unroll
        for (int p = 0; p < 2; ++p) {
            int r = p * 64 + brow;
            *(f16x8*)(Bs + r * LDP + bcol) =
                *(const f16x8*)(W + (size_t)(nloc + r) * 1024 + k0 + bcol);
        }
        __syncthreads();

        const int kc = g * 8;
        f16x8 a[4], b[4];
        #pragma unroll
        for (int i = 0; i < 4; ++i) {
            a[i] = *(const f16x8*)(As + (wm*64 + i*16 + l15) * LDP + kc);
            b[i] = *(const f16x8*)(Bs + (wn*64 + i*16 + l15) * LDP + kc);
        }
        #pragma unroll
        for (int i = 0; i < 4; ++i)
            #pragma unroll
            for (int j = 0; j < 4; ++j)
                acc[i][j] = __builtin_amdgcn_mfma_f32_16x16x32_f16(a[i], b[j], acc[i][j], 0, 0, 0);
    }

    const int rbase = m0 + wm * 64 + g * 4;
    const int cbase = nloc + wn * 64 + l15;
    if (seg < 2) {
        // Q,K: RoPE via adjacent-lane pairing (col parity == lane parity)
        #pragma unroll
        for (int j = 0; j < 4; ++j) {
            const int o  = cbase + j * 16;        // col within segment
            const int hh = o >> 6;
            const int d  = o & 63;
            const float freq = powf(10000.f, -(float)(d >> 1) * (1.f / 32.f));
            #pragma unroll
            for (int i = 0; i < 4; ++i) {
                #pragma unroll
                for (int r = 0; r < 4; ++r) {
                    const int row = rbase + i * 16 + r;
                    const int b   = row >> 11;
                    const int s   = row & 2047;
                    float v = acc[i][j][r];
                    float partner = __shfl_xor(v, 1);
                    float ang = (float)s * freq;
                    float sn, cs;
                    sincosf(ang, &sn, &cs);
                    float outv = (d & 1) ? (partner * sn + v * cs) : (v * cs - partner * sn);
                    Out[((size_t)(b * NH + hh) * SEQ + s) * DK + d] = (f16)outv;
                }
            }
        }
    } else {
        // V: transpose tile through LDS (two 64-col passes), coalesced V^T store.
        constexpr int LDT = 65;
        const int s0 = m0 & 2047;
        const int bb = m0 >> 11;
        f16* Ts = SM;                    // 128 x 65 f16 = 16640 B
        #pragma unroll
        for (int h = 0; h < 2; ++h) {
            __syncthreads();
            if (wn == h) {
                #pragma unroll
                for (int j = 0; j < 4; ++j)
                    #pragma unroll
                    for (int i = 0; i < 4; ++i)
                        #pragma unroll
                        for (int r = 0; r < 4; ++r) {
                            const int rl = wm * 64 + i * 16 + g * 4 + r;   // s-local
                            const int cl = j * 16 + l15;                   // d-local
                            Ts[rl * LDT + cl] = (f16)acc[i][j][r];
                        }
            }
            __syncthreads();
            const int hh = (nloc >> 6) + h;
            #pragma unroll
            for (int it = 0; it < 4; ++it) {
                const int c  = tid + it * 256;
                const int dl = c >> 4;            // 0..63
                const int sc = (c & 15) * 8;      // 0..120
                f16x8 v;
                #pragma unroll
                for (int e = 0; e < 8; ++e) v[e] = Ts[(sc + e) * LDT + dl];
                *(f16x8*)(Out + ((size_t)((bb * NH + hh) * DK + dl)) * SEQ + s0 + sc) = v;
            }
        }
    }
}

// ---------------------------------------------------------------------------
// Flash attention, in-register online softmax (unchanged from R13).
// ---------------------------------------------------------------------------
__global__ __launch_bounds__(256) void attn(const f16* __restrict__ Q,
                                            const f16* __restrict__ K,
                                            const f16* __restrict__ VT,
                                            f16* __restrict__ O)
{
    constexpr int SP = 72;              // f16 stride = 144B (16B aligned)
    __shared__ f16 Kt[64 * SP];
    __shared__ f16 Vt[64 * SP];         // [d][k]
    __shared__ f16 Pt[64 * SP];

    const int tid  = threadIdx.x;
    const int lane = tid & 63;
    const int w    = tid >> 6;
    const int g    = lane >> 4;         // 0..3
    const int l15  = lane & 15;
    const int qb = gridDim.x - 1 - blockIdx.x;   // heavy-first
    const int hh = blockIdx.y, b = blockIdx.z;
    const int q0 = qb * 64;
    const size_t base = (size_t)(b * NH + hh) * SEQ * DK;

    f16x8 qf[2];
    {
        const f16* qp = Q + base + (size_t)(q0 + w * 16 + l15) * DK + g * 8;
        qf[0] = *(const f16x8*)(qp);
        qf[1] = *(const f16x8*)(qp + 32);
    }
    f32x4 acc[4] = {};
    float m_reg[4] = {-INFINITY, -INFINITY, -INFINITY, -INFINITY};
    float l_reg[4] = {0.f, 0.f, 0.f, 0.f};

    const int srow = tid >> 3;          // 0..31
    const int sco  = (tid & 7) * 8;     // 0..56

    for (int kb = 0; kb <= qb; ++kb) {
        __syncthreads();
        {
            #pragma unroll
            for (int it = 0; it < 2; ++it) {
                const int rr = it * 32 + srow;  // 0..63
                f16x8 kv = *(const f16x8*)(K + base + (size_t)(kb * 64 + rr) * DK + sco);
                *(f16x8*)(Kt + rr * SP + sco) = kv;
                f16x8 vv = *(const f16x8*)(VT + base + (size_t)rr * SEQ + kb * 64 + sco);
                *(f16x8*)(Vt + rr * SP + sco) = vv;
            }
        }
        __syncthreads();

        f32x4 s[4];
        #pragma unroll
        for (int nt = 0; nt < 4; ++nt) {
            f32x4 z = {};
            const f16* kp = Kt + (nt * 16 + l15) * SP + g * 8;
            z = __builtin_amdgcn_mfma_f32_16x16x32_f16(qf[0], *(const f16x8*)kp,        z, 0, 0, 0);
            z = __builtin_amdgcn_mfma_f32_16x16x32_f16(qf[1], *(const f16x8*)(kp + 32), z, 0, 0, 0);
            s[nt] = z;
        }

        #pragma unroll
        for (int r = 0; r < 4; ++r) {
            const int qloc = w * 16 + g * 4 + r;
            float va[4];
            #pragma unroll
            for (int nt = 0; nt < 4; ++nt) {
                float sv = s[nt][r] * 0.125f;
                if (kb == qb && (nt * 16 + l15) > qloc) sv = -INFINITY;
                va[nt] = sv;
            }
            float mx = fmaxf(fmaxf(va[0], va[1]), fmaxf(va[2], va[3]));
            mx = fmaxf(mx, __shfl_xor(mx, 1));
            mx = fmaxf(mx, __shfl_xor(mx, 2));
            mx = fmaxf(mx, __shfl_xor(mx, 4));
            mx = fmaxf(mx, __shfl_xor(mx, 8));
            const float mnew = fmaxf(m_reg[r], mx);
            const float scl  = __expf(m_reg[r] - mnew);
            m_reg[r] = mnew;
            float ps = 0.f;
            #pragma unroll
            for (int nt = 0; nt < 4; ++nt) {
                float p = __expf(va[nt] - mnew);
                ps += p;
                Pt[qloc * SP + nt * 16 + l15] = (f16)p;
            }
            ps += __shfl_xor(ps, 1);
            ps += __shfl_xor(ps, 2);
            ps += __shfl_xor(ps, 4);
            ps += __shfl_xor(ps, 8);
            l_reg[r] = l_reg[r] * scl + ps;
            #pragma unroll
            for (int nt = 0; nt < 4; ++nt) acc[nt][r] *= scl;
        }

        {
            f16x8 pa[2];
            const f16* pp = Pt + (w * 16 + l15) * SP + g * 8;
            pa[0] = *(const f16x8*)pp;
            pa[1] = *(const f16x8*)(pp + 32);
            #pragma unroll
            for (int nt = 0; nt < 4; ++nt) {
                const f16* vp = Vt + (nt * 16 + l15) * SP + g * 8;
                acc[nt] = __builtin_amdgcn_mfma_f32_16x16x32_f16(pa[0], *(const f16x8*)vp,        acc[nt], 0, 0, 0);
                acc[nt] = __builtin_amdgcn_mfma_f32_16x16x32_f16(pa[1], *(const f16x8*)(vp + 32), acc[nt], 0, 0, 0);
            }
        }
    }

    #pragma unroll
    for (int r = 0; r < 4; ++r) {
        const float inv = 1.f / l_reg[r];
        const int s = q0 + w * 16 + g * 4 + r;
        #pragma unroll
        for (int nt = 0; nt < 4; ++nt) {
            const int d = nt * 16 + l15;
            O[((size_t)(b * SEQ + s)) * D_MODEL + hh * 64 + d] = (f16)(acc[nt][r] * inv);
        }
    }
}

// ---------------------------------------------------------------------------
// GEMM2: out(f32) = AO(f16)[4096][1024] @ Woh(f16)[1024][1024]^T
// BM=64, BN=128. 1D grid 512, XCD-bijective swizzle (64 wgids/XCD).
// ---------------------------------------------------------------------------
__global__ __launch_bounds__(256) void gemm_out(const f16* __restrict__ A,
                                                const f16* __restrict__ W,
                                                float* __restrict__ Cout)
{
    constexpr int BK  = 32;
    constexpr int LDP = BK + 8;
    __shared__ f16 As[64 * LDP];
    __shared__ f16 Bs[128 * LDP];

    const int tid  = threadIdx.x;
    const int lane = tid & 63;
    const int wave = tid >> 6;
    const int wm   = wave >> 1, wn = wave & 1;     // wave tile 32x64
    const int wg   = blockIdx.x;
    const int wgid = (wg & 7) * 64 + (wg >> 3);
    const int m0   = (wgid >> 3) * 64;
    const int n0   = (wgid & 7) * 128;

    f32x4 acc[2][4] = {};

    const int arow = tid >> 2;        // 0..63 (A stage)
    const int acol = (tid & 3) * 8;
    const int brow = tid >> 2;        // 0..63 (B stage, f16, 2 passes)
    const int bcol = (tid & 3) * 8;

    for (int k0 = 0; k0 < 1024; k0 += BK) {
        __syncthreads();
        {
            f16x8 v = *(const f16x8*)(A + (size_t)(m0 + arow) * 1024 + k0 + acol);
            *(f16x8*)(As + arow * LDP + acol) = v;
        }
        #pragma unroll
        for (int p = 0; p < 2; ++p) {
            int r = p * 64 + brow;
            *(f16x8*)(Bs + r * LDP + bcol) =
                *(const f16x8*)(W + (size_t)(n0 + r) * 1024 + k0 + bcol);
        }
        __syncthreads();

        const int kc = (lane >> 4) * 8;
        f16x8 a[2], b[4];
        #pragma unroll
        for (int i = 0; i < 2; ++i)
            a[i] = *(const f16x8*)(As + (wm*32 + i*16 + (lane & 15)) * LDP + kc);
        #pragma unroll
        for (int j = 0; j < 4; ++j)
            b[j] = *(const f16x8*)(Bs + (wn*64 + j*16 + (lane & 15)) * LDP + kc);
        #pragma unroll
        for (int i = 0; i < 2; ++i)
            #pragma unroll
            for (int j = 0; j < 4; ++j)
                acc[i][j] = __builtin_amdgcn_mfma_f32_16x16x32_f16(a[i], b[j], acc[i][j], 0, 0, 0);
    }

    #pragma unroll
    for (int i = 0; i < 2; ++i)
        #pragma unroll
        for (int j = 0; j < 4; ++j)
            #pragma unroll
            for (int r = 0; r < 4; ++r) {
                const int row = m0 + wm*32 + i*16 + ((lane >> 4) * 4) + r;
                const int col = n0 + wn*64 + j*16 + (lane & 15);
                Cout[(size_t)row * 1024 + col] = acc[i][j][r];
            }
}

// ---------------------------------------------------------------------------
extern "C" void kernel_launch(void* const* d_in, const int* in_sizes, int n_in,
                              void* d_out, int out_size, void* d_ws, size_t ws_size,
                              hipStream_t stream)
{
    const float* x  = (const float*)d_in[0];
    const float* Wq = (const float*)d_in[1];
    const float* Wk = (const float*)d_in[2];
    const float* Wv = (const float*)d_in[3];
    const float* Wo = (const float*)d_in[4];
    float* out = (float*)d_out;

    const size_t NE = (size_t)BATCH * SEQ * D_MODEL;  // 4194304
    f16* Qr  = (f16*)d_ws;
    f16* Kr  = Qr + NE;
    f16* VTr = Kr + NE;   // transposed V: [b][h][d][s]
    f16* AO  = VTr + NE;
    f16* Wh  = AO + NE;   // 4 x 1M f16 converted weights (8 MB)

    dim3 blk(256);
    tof16<<<2048, blk, 0, stream>>>(Wq, Wk, Wv, Wo, Wh);

    gemm_qkv<<<768, blk, 0, stream>>>(x, Wh, Qr);

    attn<<<dim3(SEQ / 64, NH, BATCH), blk, 0, stream>>>(Qr, Kr, VTr, AO);

    gemm_out<<<512, blk, 0, stream>>>(AO, Wh + 3 * 1048576, out);
}

// Round 16
// 326.394 us; speedup vs baseline: 2.7159x; 2.3126x over previous
//
#include <hip/hip_runtime.h>
#include <hip/hip_fp16.h>

#define BATCH 2
#define D_MODEL 1024
#define NH 16
#define DK 64
#define SEQ 2048

typedef _Float16 f16;
typedef __attribute__((ext_vector_type(8))) _Float16 f16x8;
typedef __attribute__((ext_vector_type(4))) _Float16 f16x4;
typedef __attribute__((ext_vector_type(4))) float f32x4;

// ---------------------------------------------------------------------------
// tof16: convert Wq,Wk,Wv,Wo (each 1024x1024 f32) to f16 into Wh (contiguous).
// ---------------------------------------------------------------------------
__global__ __launch_bounds__(256) void tof16(const float* __restrict__ a,
                                             const float* __restrict__ b,
                                             const float* __restrict__ c,
                                             const float* __restrict__ d,
                                             f16* __restrict__ dst)
{
    const int u = blockIdx.x;           // 0..2047
    const int m = u >> 9;               // matrix id
    const float* __restrict__ src = (m == 0) ? a : (m == 1) ? b : (m == 2) ? c : d;
    const int off = (u & 511) * 2048 + threadIdx.x * 8;
    float4 v0 = *(const float4*)(src + off);
    float4 v1 = *(const float4*)(src + off + 4);
    f16x8 h;
    h[0]=(f16)v0.x; h[1]=(f16)v0.y; h[2]=(f16)v0.z; h[3]=(f16)v0.w;
    h[4]=(f16)v1.x; h[5]=(f16)v1.y; h[6]=(f16)v1.z; h[7]=(f16)v1.w;
    *(f16x8*)(dst + (size_t)m * 1048576 + off) = h;
}

// ---------------------------------------------------------------------------
// ropetab: tab[s*32+p] = (cos(s*freq_p), sin(s*freq_p)), freq_p=10000^(-p/32)
// 65536 entries, 256 blocks x 256 threads.
// ---------------------------------------------------------------------------
__global__ __launch_bounds__(256) void ropetab(float2* __restrict__ tab)
{
    const int i = blockIdx.x * 256 + threadIdx.x;   // 0..65535
    const int s = i >> 5, p = i & 31;
    const float freq = powf(10000.f, -(float)p * (1.f / 32.f));
    const float ang  = (float)s * freq;
    float sn, cs;
    sincosf(ang, &sn, &cs);
    tab[i] = make_float2(cs, sn);
}

// ---------------------------------------------------------------------------
// Fused QKV GEMM: C = X(f32)[4096][1024] @ Wh(f16)^T -> N = 3072.
// Unified 2-phase LDS epilogue: acc -> LDS tile (acc dies), then coalesced
// f16x8 global stores.  Q,K: [b][h][s][dk] with table-RoPE applied in-thread
// (pairs are adjacent d, held by one thread).  V: transposed [b][h][d][s].
// 128x128 tile, BK=32, 4 waves (2x2). 1D grid 768, XCD-bijective swizzle.
// ---------------------------------------------------------------------------
__global__ __launch_bounds__(256, 2) void gemm_qkv(const float* __restrict__ X,
                                                   const f16* __restrict__ Wh,
                                                   const float2* __restrict__ tab,
                                                   f16* __restrict__ WS)
{
    constexpr int BK  = 32;
    constexpr int LDP = BK + 8;  // 80B rows
    constexpr int LDT = 65;
    __shared__ f16 SM[2 * 128 * LDP];   // 20480 B; epilogue reuses as Ts[128][65]
    f16* As = SM;
    f16* Bs = SM + 128 * LDP;
    f16* Ts = SM;

    const int tid  = threadIdx.x;
    const int lane = tid & 63;
    const int wave = tid >> 6;
    const int wm   = wave >> 1, wn = wave & 1;
    const int g    = lane >> 4;
    const int l15  = lane & 15;

    // XCD-bijective swizzle (768 % 8 == 0; 96 contiguous wgids per XCD)
    const int wg   = blockIdx.x;
    const int wgid = (wg & 7) * 96 + (wg >> 3);
    const int bx   = wgid % 24;
    const int by   = wgid / 24;
    const int m0   = by * 128;
    const int n0   = bx * 128;             // 0..3071
    const int seg  = n0 >> 10;             // 0=Q 1=K 2=V
    const int nloc = n0 & 1023;
    const f16* __restrict__ W = Wh + (size_t)seg * 1048576;
    f16* __restrict__ Out = WS + (size_t)seg * BATCH * SEQ * D_MODEL;

    f32x4 acc[4][4] = {};

    const int srow = tid >> 3;        // 0..31  (A stage, f32)
    const int scol = (tid & 7) * 4;
    const int brow = tid >> 2;        // 0..63  (B stage, f16)
    const int bcol = (tid & 3) * 8;

    for (int k0 = 0; k0 < 1024; k0 += BK) {
        __syncthreads();
        #pragma unroll
        for (int p = 0; p < 4; ++p) {
            int r = p * 32 + srow;
            float4 v = *(const float4*)(X + (size_t)(m0 + r) * 1024 + k0 + scol);
            f16x4 h; h[0]=(f16)v.x; h[1]=(f16)v.y; h[2]=(f16)v.z; h[3]=(f16)v.w;
            *(f16x4*)(As + r * LDP + scol) = h;
        }
        #pragma unroll
        for (int p = 0; p < 2; ++p) {
            int r = p * 64 + brow;
            *(f16x8*)(Bs + r * LDP + bcol) =
                *(const f16x8*)(W + (size_t)(nloc + r) * 1024 + k0 + bcol);
        }
        __syncthreads();

        const int kc = g * 8;
        f16x8 a[4], b[4];
        #pragma unroll
        for (int i = 0; i < 4; ++i) {
            a[i] = *(const f16x8*)(As + (wm*64 + i*16 + l15) * LDP + kc);
            b[i] = *(const f16x8*)(Bs + (wn*64 + i*16 + l15) * LDP + kc);
        }
        #pragma unroll
        for (int i = 0; i < 4; ++i)
            #pragma unroll
            for (int j = 0; j < 4; ++j)
                acc[i][j] = __builtin_amdgcn_mfma_f32_16x16x32_f16(a[i], b[j], acc[i][j], 0, 0, 0);
    }

    // ---- unified 2-phase epilogue: acc -> Ts (dies), then coalesced out ----
    const int bb = m0 >> 11;          // batch
    const int s0 = m0 & 2047;         // s of tile row 0
    #pragma unroll
    for (int h = 0; h < 2; ++h) {
        __syncthreads();
        if (wn == h) {
            #pragma unroll
            for (int j = 0; j < 4; ++j)
                #pragma unroll
                for (int i = 0; i < 4; ++i)
                    #pragma unroll
                    for (int r = 0; r < 4; ++r) {
                        const int rl = wm * 64 + i * 16 + g * 4 + r;   // row-local
                        const int cl = j * 16 + l15;                   // col-local 0..63
                        Ts[rl * LDT + cl] = (f16)acc[i][j][r];
                    }
        }
        __syncthreads();
        const int hh = (nloc >> 6) + h;
        if (seg < 2) {
            // Q,K: rows out, in-thread RoPE on 4 (even,odd) pairs
            #pragma unroll
            for (int it = 0; it < 4; ++it) {
                const int c   = tid + it * 256;
                const int row = c >> 3;            // 0..127 over 4 iters
                const int dc  = (c & 7) * 8;       // 0..56
                const int s   = s0 + row;
                f16x8 v = *(const f16x8*)(Ts + row * LDT + dc);
                const float2* tp = tab + s * 32 + (dc >> 1);
                f16x8 o;
                #pragma unroll
                for (int e = 0; e < 8; e += 2) {
                    const float2 cs = tp[e >> 1];
                    const float xe = (float)v[e], xo = (float)v[e + 1];
                    o[e]     = (f16)(xe * cs.x - xo * cs.y);
                    o[e + 1] = (f16)(xe * cs.y + xo * cs.x);
                }
                *(f16x8*)(Out + ((size_t)(bb * NH + hh) * SEQ + s) * DK + dc) = o;
            }
        } else {
            // V: transposed out [b][h][d][s]
            #pragma unroll
            for (int it = 0; it < 4; ++it) {
                const int c  = tid + it * 256;
                const int dl = c >> 4;             // 0..63
                const int sc = (c & 15) * 8;       // 0..120
                f16x8 v;
                #pragma unroll
                for (int e = 0; e < 8; ++e) v[e] = Ts[(sc + e) * LDT + dl];
                *(f16x8*)(Out + ((size_t)((bb * NH + hh) * DK + dl)) * SEQ + s0 + sc) = v;
            }
        }
    }
}

// ---------------------------------------------------------------------------
// Flash attention, in-register online softmax (unchanged, passing since R9).
// ---------------------------------------------------------------------------
__global__ __launch_bounds__(256) void attn(const f16* __restrict__ Q,
                                            const f16* __restrict__ K,
                                            const f16* __restrict__ VT,
                                            f16* __restrict__ O)
{
    constexpr int SP = 72;
    __shared__ f16 Kt[64 * SP];
    __shared__ f16 Vt[64 * SP];
    __shared__ f16 Pt[64 * SP];

    const int tid  = threadIdx.x;
    const int lane = tid & 63;
    const int w    = tid >> 6;
    const int g    = lane >> 4;
    const int l15  = lane & 15;
    const int qb = gridDim.x - 1 - blockIdx.x;   // heavy-first
    const int hh = blockIdx.y, b = blockIdx.z;
    const int q0 = qb * 64;
    const size_t base = (size_t)(b * NH + hh) * SEQ * DK;

    f16x8 qf[2];
    {
        const f16* qp = Q + base + (size_t)(q0 + w * 16 + l15) * DK + g * 8;
        qf[0] = *(const f16x8*)(qp);
        qf[1] = *(const f16x8*)(qp + 32);
    }
    f32x4 acc[4] = {};
    float m_reg[4] = {-INFINITY, -INFINITY, -INFINITY, -INFINITY};
    float l_reg[4] = {0.f, 0.f, 0.f, 0.f};

    const int srow = tid >> 3;
    const int sco  = (tid & 7) * 8;

    for (int kb = 0; kb <= qb; ++kb) {
        __syncthreads();
        {
            #pragma unroll
            for (int it = 0; it < 2; ++it) {
                const int rr = it * 32 + srow;
                f16x8 kv = *(const f16x8*)(K + base + (size_t)(kb * 64 + rr) * DK + sco);
                *(f16x8*)(Kt + rr * SP + sco) = kv;
                f16x8 vv = *(const f16x8*)(VT + base + (size_t)rr * SEQ + kb * 64 + sco);
                *(f16x8*)(Vt + rr * SP + sco) = vv;
            }
        }
        __syncthreads();

        f32x4 s[4];
        #pragma unroll
        for (int nt = 0; nt < 4; ++nt) {
            f32x4 z = {};
            const f16* kp = Kt + (nt * 16 + l15) * SP + g * 8;
            z = __builtin_amdgcn_mfma_f32_16x16x32_f16(qf[0], *(const f16x8*)kp,        z, 0, 0, 0);
            z = __builtin_amdgcn_mfma_f32_16x16x32_f16(qf[1], *(const f16x8*)(kp + 32), z, 0, 0, 0);
            s[nt] = z;
        }

        #pragma unroll
        for (int r = 0; r < 4; ++r) {
            const int qloc = w * 16 + g * 4 + r;
            float va[4];
            #pragma unroll
            for (int nt = 0; nt < 4; ++nt) {
                float sv = s[nt][r] * 0.125f;
                if (kb == qb && (nt * 16 + l15) > qloc) sv = -INFINITY;
                va[nt] = sv;
            }
            float mx = fmaxf(fmaxf(va[0], va[1]), fmaxf(va[2], va[3]));
            mx = fmaxf(mx, __shfl_xor(mx, 1));
            mx = fmaxf(mx, __shfl_xor(mx, 2));
            mx = fmaxf(mx, __shfl_xor(mx, 4));
            mx = fmaxf(mx, __shfl_xor(mx, 8));
            const float mnew = fmaxf(m_reg[r], mx);
            const float scl  = __expf(m_reg[r] - mnew);
            m_reg[r] = mnew;
            float ps = 0.f;
            #pragma unroll
            for (int nt = 0; nt < 4; ++nt) {
                float p = __expf(va[nt] - mnew);
                ps += p;
                Pt[qloc * SP + nt * 16 + l15] = (f16)p;
            }
            ps += __shfl_xor(ps, 1);
            ps += __shfl_xor(ps, 2);
            ps += __shfl_xor(ps, 4);
            ps += __shfl_xor(ps, 8);
            l_reg[r] = l_reg[r] * scl + ps;
            #pragma unroll
            for (int nt = 0; nt < 4; ++nt) acc[nt][r] *= scl;
        }

        {
            f16x8 pa[2];
            const f16* pp = Pt + (w * 16 + l15) * SP + g * 8;
            pa[0] = *(const f16x8*)pp;
            pa[1] = *(const f16x8*)(pp + 32);
            #pragma unroll
            for (int nt = 0; nt < 4; ++nt) {
                const f16* vp = Vt + (nt * 16 + l15) * SP + g * 8;
                acc[nt] = __builtin_amdgcn_mfma_f32_16x16x32_f16(pa[0], *(const f16x8*)vp,        acc[nt], 0, 0, 0);
                acc[nt] = __builtin_amdgcn_mfma_f32_16x16x32_f16(pa[1], *(const f16x8*)(vp + 32), acc[nt], 0, 0, 0);
            }
        }
    }

    #pragma unroll
    for (int r = 0; r < 4; ++r) {
        const float inv = 1.f / l_reg[r];
        const int s = q0 + w * 16 + g * 4 + r;
        #pragma unroll
        for (int nt = 0; nt < 4; ++nt) {
            const int d = nt * 16 + l15;
            O[((size_t)(b * SEQ + s)) * D_MODEL + hh * 64 + d] = (f16)(acc[nt][r] * inv);
        }
    }
}

// ---------------------------------------------------------------------------
// GEMM2: out(f32) = AO(f16)[4096][1024] @ Woh(f16)[1024][1024]^T
// BM=64, BN=128. 1D grid 512, XCD-bijective swizzle.
// ---------------------------------------------------------------------------
__global__ __launch_bounds__(256) void gemm_out(const f16* __restrict__ A,
                                                const f16* __restrict__ W,
                                                float* __restrict__ Cout)
{
    constexpr int BK  = 32;
    constexpr int LDP = BK + 8;
    __shared__ f16 As[64 * LDP];
    __shared__ f16 Bs[128 * LDP];

    const int tid  = threadIdx.x;
    const int lane = tid & 63;
    const int wave = tid >> 6;
    const int wm   = wave >> 1, wn = wave & 1;
    const int wg   = blockIdx.x;
    const int wgid = (wg & 7) * 64 + (wg >> 3);
    const int m0   = (wgid >> 3) * 64;
    const int n0   = (wgid & 7) * 128;

    f32x4 acc[2][4] = {};

    const int arow = tid >> 2;
    const int acol = (tid & 3) * 8;

    for (int k0 = 0; k0 < 1024; k0 += BK) {
        __syncthreads();
        {
            f16x8 v = *(const f16x8*)(A + (size_t)(m0 + arow) * 1024 + k0 + acol);
            *(f16x8*)(As + arow * LDP + acol) = v;
        }
        #pragma unroll
        for (int p = 0; p < 2; ++p) {
            int r = p * 64 + arow;
            *(f16x8*)(Bs + r * LDP + acol) =
                *(const f16x8*)(W + (size_t)(n0 + r) * 1024 + k0 + acol);
        }
        __syncthreads();

        const int kc = (lane >> 4) * 8;
        f16x8 a[2], b[4];
        #pragma unroll
        for (int i = 0; i < 2; ++i)
            a[i] = *(const f16x8*)(As + (wm*32 + i*16 + (lane & 15)) * LDP + kc);
        #pragma unroll
        for (int j = 0; j < 4; ++j)
            b[j] = *(const f16x8*)(Bs + (wn*64 + j*16 + (lane & 15)) * LDP + kc);
        #pragma unroll
        for (int i = 0; i < 2; ++i)
            #pragma unroll
            for (int j = 0; j < 4; ++j)
                acc[i][j] = __builtin_amdgcn_mfma_f32_16x16x32_f16(a[i], b[j], acc[i][j], 0, 0, 0);
    }

    #pragma unroll
    for (int i = 0; i < 2; ++i)
        #pragma unroll
        for (int j = 0; j < 4; ++j)
            #pragma unroll
            for (int r = 0; r < 4; ++r) {
                const int row = m0 + wm*32 + i*16 + ((lane >> 4) * 4) + r;
                const int col = n0 + wn*64 + j*16 + (lane & 15);
                Cout[(size_t)row * 1024 + col] = acc[i][j][r];
            }
}

// ---------------------------------------------------------------------------
extern "C" void kernel_launch(void* const* d_in, const int* in_sizes, int n_in,
                              void* d_out, int out_size, void* d_ws, size_t ws_size,
                              hipStream_t stream)
{
    const float* x  = (const float*)d_in[0];
    const float* Wq = (const float*)d_in[1];
    const float* Wk = (const float*)d_in[2];
    const float* Wv = (const float*)d_in[3];
    const float* Wo = (const float*)d_in[4];
    float* out = (float*)d_out;

    const size_t NE = (size_t)BATCH * SEQ * D_MODEL;  // 4194304
    f16* Qr  = (f16*)d_ws;
    f16* Kr  = Qr + NE;
    f16* VTr = Kr + NE;           // transposed V: [b][h][d][s]
    f16* AO  = VTr + NE;
    f16* Wh  = AO + NE;           // 4 x 1M f16 weights (8 MB)
    float2* tab = (float2*)(Wh + 4 * 1048576);  // 2048x32 cos/sin (512 KB)

    dim3 blk(256);
    tof16<<<2048, blk, 0, stream>>>(Wq, Wk, Wv, Wo, Wh);
    ropetab<<<256, blk, 0, stream>>>(tab);

    gemm_qkv<<<768, blk, 0, stream>>>(x, Wh, tab, Qr);

    attn<<<dim3(SEQ / 64, NH, BATCH), blk, 0, stream>>>(Qr, Kr, VTr, AO);

    gemm_out<<<512, blk, 0, stream>>>(AO, Wh + 3 * 1048576, out);
}